// Round 5
// baseline (486.206 us; speedup 1.0000x reference)
//
#include <hip/hip_runtime.h>
#include <math.h>

// Problem constants
#define B 32
#define N 4096
#define D 128
#define KTOP 512
#define NPB 2048
#define MSEG (B * NPB)      // 65536
#define E (B * N)           // 131072
#define MAXC 32             // max edges per segment
#define K7ROWS 16           // rows per k7 block

// ---------------------------------------------------------------------------
// K0: per-batch precompute (fp64): query = cat(qh,qr,qt)@W_q+b_q,
// u_d = q_d*W1_d - W2_d + W3_d, v = W_a @ u, c2 = q.(W2+W3)+b_att+b_a.u
// ---------------------------------------------------------------------------
__global__ __launch_bounds__(128) void k0_precompute(
    const float* __restrict__ qh, const float* __restrict__ qr,
    const float* __restrict__ qt, const float* __restrict__ Wq,
    const float* __restrict__ bq, const float* __restrict__ Wa,
    const float* __restrict__ ba, const float* __restrict__ Watt,
    const float* __restrict__ batt, float* __restrict__ vf,
    float* __restrict__ c2f) {
  int b = blockIdx.x, d = threadIdx.x;
  __shared__ double u[128];
  __shared__ double red[128];
  const float* qhb = qh + b * 128;
  const float* qrb = qr + b * 128;
  const float* qtb = qt + b * 128;
  double a0 = 0, a1 = 0, a2 = 0, a3 = 0;
#pragma unroll 4
  for (int i = 0; i < 128; i += 4) {
    a0 += (double)qhb[i] * (double)Wq[i * 128 + d];
    a1 += (double)qhb[i + 1] * (double)Wq[(i + 1) * 128 + d];
    a2 += (double)qhb[i + 2] * (double)Wq[(i + 2) * 128 + d];
    a3 += (double)qhb[i + 3] * (double)Wq[(i + 3) * 128 + d];
  }
#pragma unroll 4
  for (int i = 0; i < 128; i += 4) {
    a0 += (double)qrb[i] * (double)Wq[(128 + i) * 128 + d];
    a1 += (double)qrb[i + 1] * (double)Wq[(129 + i) * 128 + d];
    a2 += (double)qrb[i + 2] * (double)Wq[(130 + i) * 128 + d];
    a3 += (double)qrb[i + 3] * (double)Wq[(131 + i) * 128 + d];
  }
#pragma unroll 4
  for (int i = 0; i < 128; i += 4) {
    a0 += (double)qtb[i] * (double)Wq[(256 + i) * 128 + d];
    a1 += (double)qtb[i + 1] * (double)Wq[(257 + i) * 128 + d];
    a2 += (double)qtb[i + 2] * (double)Wq[(258 + i) * 128 + d];
    a3 += (double)qtb[i + 3] * (double)Wq[(259 + i) * 128 + d];
  }
  double acc = (double)bq[d] + ((a0 + a1) + (a2 + a3));
  double w1 = (double)Watt[d], w2 = (double)Watt[128 + d], w3 = (double)Watt[256 + d];
  double ud = acc * w1 - w2 + w3;
  u[d] = ud;
  red[d] = acc * (w2 + w3) + (double)ba[d] * ud;
  __syncthreads();
  for (int s = 64; s > 0; s >>= 1) {
    if (d < s) red[d] += red[d + s];
    __syncthreads();
  }
  if (d == 0) c2f[b] = (float)(red[0] + (double)batt[0]);
  for (int i = d; i < 384; i += 128) {
    double v0 = 0, v1 = 0, v2 = 0, v3 = 0;
#pragma unroll 4
    for (int dd = 0; dd < 128; dd += 4) {
      v0 += (double)Wa[i * 128 + dd] * u[dd];
      v1 += (double)Wa[i * 128 + dd + 1] * u[dd + 1];
      v2 += (double)Wa[i * 128 + dd + 2] * u[dd + 2];
      v3 += (double)Wa[i * 128 + dd + 3] * u[dd + 3];
    }
    vf[b * 384 + i] = (float)((v0 + v1) + (v2 + v3));
  }
}

// ---------------------------------------------------------------------------
// K1: per-edge attention + fused list build. 4 lanes per edge, float4/lane,
// 8 chunk-iterations; only 2 shfl_xor rounds per edge.
// Block 256 threads = 64 edges (same batch). v/wrule staged in 2KB LDS.
// Epilogue (q==0): attw write, fp64 agg atomic, counts/list build.
// ---------------------------------------------------------------------------
__global__ __launch_bounds__(256) void k1_att(
    const float* __restrict__ r, const float* __restrict__ t,
    const float* __restrict__ tm, const float* __restrict__ hidden,
    const float* __restrict__ Wrule, const float* __restrict__ brule,
    const float* __restrict__ vf, const float* __restrict__ c2f,
    const int* __restrict__ tidx, float* __restrict__ attw,
    double* __restrict__ aggd, int* __restrict__ counts,
    int* __restrict__ lists) {
  __shared__ float sAll[512];  // [0,384): v ; [384,512): Wrule
  int tid = threadIdx.x;
  int base = blockIdx.x * 64;
  int b = base >> 12;  // batch, uniform over block
  // stage v + Wrule (boundary test per index — R4 bug was here)
  for (int i = tid; i < 512; i += 256)
    sAll[i] = (i < 384) ? vf[b * 384 + i] : Wrule[i - 384];
  __syncthreads();
  int q = tid & 3;         // quad lane
  int e = base + (tid >> 2);
  float4 acc1 = make_float4(0.f, 0.f, 0.f, 0.f);
  float4 acc2 = make_float4(0.f, 0.f, 0.f, 0.f);
  size_t erow = (size_t)e * 128;
#pragma unroll
  for (int i = 0; i < 8; ++i) {
    int co = i * 16 + q * 4;
    float4 v0 = *(const float4*)&sAll[co];
    float4 v1 = *(const float4*)&sAll[128 + co];
    float4 v2 = *(const float4*)&sAll[256 + co];
    float4 w4 = *(const float4*)&sAll[384 + co];
    float4 ra = *(const float4*)(r + erow + co);
    float4 ta = *(const float4*)(t + erow + co);
    float4 ma = *(const float4*)(tm + erow + co);
    float4 ha = *(const float4*)(hidden + erow + co);
    acc1.x += ra.x * v0.x + ta.x * v1.x + ma.x * v2.x;
    acc1.y += ra.y * v0.y + ta.y * v1.y + ma.y * v2.y;
    acc1.z += ra.z * v0.z + ta.z * v1.z + ma.z * v2.z;
    acc1.w += ra.w * v0.w + ta.w * v1.w + ma.w * v2.w;
    acc2.x += ha.x * w4.x;
    acc2.y += ha.y * w4.y;
    acc2.z += ha.z * w4.z;
    acc2.w += ha.w * w4.w;
  }
  float p1 = (acc1.x + acc1.y) + (acc1.z + acc1.w);
  float p2 = (acc2.x + acc2.y) + (acc2.z + acc2.w);
  p1 += __shfl_xor(p1, 1);
  p2 += __shfl_xor(p2, 1);
  p1 += __shfl_xor(p1, 2);
  p2 += __shfl_xor(p2, 2);
  if (q == 0) {
    float a1 = 1.0f / (1.0f + expf(-(p1 + c2f[b])));
    float a2 = 1.0f / (1.0f + expf(-(p2 + brule[0])));
    float a = 0.5f * (a1 + a2);
    attw[e] = a;
    int m = tidx[e];
    atomicAdd(&aggd[m], (double)a);
    int pos = atomicAdd(&counts[m], 1);
    if (pos < MAXC) lists[m * MAXC + pos] = e;
  }
}

// ---------------------------------------------------------------------------
// K6: exact top-K by rank counting on fp64 agg. Block = (batch, 256 elems).
// rank(i) = #{j : v_j > v_i || (v_j == v_i && j < i)}  == lax.top_k position.
// ---------------------------------------------------------------------------
__global__ __launch_bounds__(256) void k6_topk(
    const double* __restrict__ aggd, const int* __restrict__ tail_nodes,
    float* __restrict__ out_nodes, int* __restrict__ idxw) {
  __shared__ double sv[2048];
  int b = blockIdx.x >> 3;
  int chunk = blockIdx.x & 7;
  int tid = threadIdx.x;
  for (int s = tid; s < 2048; s += 256) sv[s] = aggd[b * 2048 + s];
  __syncthreads();
  int i = chunk * 256 + tid;
  double vi = sv[i];
  const double2* sv2 = (const double2*)sv;
  int rank = 0;
#pragma unroll 4
  for (int j2 = 0; j2 < 1024; ++j2) {
    double2 vv = sv2[j2];
    rank += (vv.x > vi) || (vv.x == vi && (2 * j2) < i);
    rank += (vv.y > vi) || (vv.y == vi && (2 * j2 + 1) < i);
  }
  if (rank < KTOP) {
    int gm = b * 2048 + i;
    int p = b * KTOP + rank;
    out_nodes[p * 2 + 0] = (float)tail_nodes[gm * 3 + 1];
    out_nodes[p * 2 + 1] = (float)tail_nodes[gm * 3 + 2];
    idxw[p] = gm;
  }
}

// ---------------------------------------------------------------------------
// K7: selected rows only. Phase 1: half-wave (32 lanes, float4/lane) per row,
// gather edges + segment sums -> es LDS + out_hid. Phase 2: GEMM
// es(16x128) @ Wout(128x128) with Wout from L2, 8 indep accs/thread.
// ---------------------------------------------------------------------------
__global__ __launch_bounds__(256) void k7_out(
    const float* __restrict__ tail_emd, const float* __restrict__ r,
    const float* __restrict__ tm, const float* __restrict__ hidden,
    const float* __restrict__ qh, const float* __restrict__ attw,
    const int* __restrict__ counts, const int* __restrict__ lists,
    const float* __restrict__ Wout, const float* __restrict__ bout,
    const int* __restrict__ idxw, float* __restrict__ out_emd,
    float* __restrict__ out_hid) {
  __shared__ float es[K7ROWS][132];  // pad 132: row stride 4 mod 32 banks
  int tid = threadIdx.x;
  int r0 = tid >> 5;    // half-wave id 0..7
  int l = tid & 31;     // lane in half-wave; covers floats l*4..l*4+3
  int base = blockIdx.x * K7ROWS;
#pragma unroll
  for (int p = 0; p < 2; ++p) {
    int row = base + p * 8 + r0;
    int m = idxw[row];
    int bb = m >> 11;
    int cnt = counts[m];
    if (cnt > MAXC) cnt = MAXC;
    float4 accT = *(const float4*)(tail_emd + (size_t)m * 128 + l * 4);
    float4 qh4 = *(const float4*)(qh + bb * 128 + l * 4);
    float4 accH = make_float4(0.f, 0.f, 0.f, 0.f);
    for (int jj = 0; jj < cnt; ++jj) {
      int e = lists[m * MAXC + jj];
      float a = attw[e];
      size_t eo = (size_t)e * 128 + l * 4;
      float4 ra = *(const float4*)(r + eo);
      float4 ma = *(const float4*)(tm + eo);
      float4 ha = *(const float4*)(hidden + eo);
      accT.x += a * (qh4.x + ra.x + ma.x);
      accT.y += a * (qh4.y + ra.y + ma.y);
      accT.z += a * (qh4.z + ra.z + ma.z);
      accT.w += a * (qh4.w + ra.w + ma.w);
      accH.x += ha.x; accH.y += ha.y; accH.z += ha.z; accH.w += ha.w;
    }
    *(float4*)&es[p * 8 + r0][l * 4] = accT;
    *(float4*)(out_hid + (size_t)row * 128 + l * 4) = accH;
  }
  __syncthreads();
  // ---- phase 2: GEMM es(16x128) @ Wout(128x128) ----
  int cg = tid & 31;   // columns cg*4 .. cg*4+3
  int rg = tid >> 5;   // row pair rg*2, rg*2+1
  float4 bo = *(const float4*)(bout + cg * 4);
  float acc0x = bo.x, acc0y = bo.y, acc0z = bo.z, acc0w = bo.w;
  float acc1x = bo.x, acc1y = bo.y, acc1z = bo.z, acc1w = bo.w;
#pragma unroll 4
  for (int i = 0; i < 128; ++i) {
    float4 w = *(const float4*)(Wout + i * 128 + cg * 4);
    float e0 = es[rg * 2 + 0][i];
    float e1 = es[rg * 2 + 1][i];
    acc0x += e0 * w.x; acc0y += e0 * w.y; acc0z += e0 * w.z; acc0w += e0 * w.w;
    acc1x += e1 * w.x; acc1y += e1 * w.y; acc1z += e1 * w.z; acc1w += e1 * w.w;
  }
  size_t o0 = (size_t)(base + rg * 2) * 128 + cg * 4;
  *(float4*)(out_emd + o0) = make_float4(acc0x, acc0y, acc0z, acc0w);
  *(float4*)(out_emd + o0 + 128) = make_float4(acc1x, acc1y, acc1z, acc1w);
}

// ---------------------------------------------------------------------------
extern "C" void kernel_launch(void* const* d_in, const int* in_sizes, int n_in,
                              void* d_out, int out_size, void* d_ws,
                              size_t ws_size, hipStream_t stream) {
  const float* q_head = (const float*)d_in[0];
  const float* q_rel = (const float*)d_in[1];
  const float* q_time = (const float*)d_in[2];
  const float* r_nb = (const float*)d_in[3];
  const float* t_nb = (const float*)d_in[4];
  const float* tm_nb = (const float*)d_in[5];
  const float* hidden = (const float*)d_in[6];
  const float* tail_emd = (const float*)d_in[7];
  const int* tail_index = (const int*)d_in[8];
  const int* tail_nodes = (const int*)d_in[9];
  const float* W_q = (const float*)d_in[10];
  const float* b_q = (const float*)d_in[11];
  const float* W_a = (const float*)d_in[12];
  const float* b_a = (const float*)d_in[13];
  const float* W_att = (const float*)d_in[14];
  const float* b_att = (const float*)d_in[15];
  const float* W_rule = (const float*)d_in[16];
  const float* b_rule = (const float*)d_in[17];
  const float* W_out = (const float*)d_in[18];
  const float* b_out = (const float*)d_in[19];

  char* ws = (char*)d_ws;
  int* counts = (int*)(ws + 0);              // M*4 = 262144
  double* aggd = (double*)(ws + 262144);     // M*8 = 524288 -> 786432
  float* vf = (float*)(ws + 786432);         // 49152 -> 835584
  float* c2f = (float*)(ws + 835584);        // 128  -> 835712
  float* attw = (float*)(ws + 835712);       // E*4 = 524288 -> 1360000
  int* lists = (int*)(ws + 1360000);         // M*32*4 = 8388608 -> 9748608
  int* idxw = (int*)(ws + 9748608);          // B*K*4 = 65536 -> 9814144

  float* out_nodes = (float*)d_out;                       // B*K*2
  float* out_emd = (float*)d_out + (size_t)B * KTOP * 2;  // B*K*128
  float* out_hid = out_emd + (size_t)B * KTOP * 128;      // B*K*128

  // counts + aggd are adjacent: one memset clears both
  hipMemsetAsync(counts, 0, 786432, stream);
  k0_precompute<<<B, 128, 0, stream>>>(q_head, q_rel, q_time, W_q, b_q, W_a,
                                       b_a, W_att, b_att, vf, c2f);
  k1_att<<<E / 64, 256, 0, stream>>>(r_nb, t_nb, tm_nb, hidden, W_rule, b_rule,
                                     vf, c2f, tail_index, attw, aggd, counts,
                                     lists);
  k6_topk<<<B * 8, 256, 0, stream>>>(aggd, tail_nodes, out_nodes, idxw);
  k7_out<<<(B * KTOP) / K7ROWS, 256, 0, stream>>>(tail_emd, r_nb, tm_nb,
                                                  hidden, q_head, attw, counts,
                                                  lists, W_out, b_out, idxw,
                                                  out_emd, out_hid);
}